// Round 1
// baseline (87.307 us; speedup 1.0000x reference)
//
#include <hip/hip_runtime.h>

// Static config (matches reference)
#define HP 24
#define WP 24
#define TF 9
#define HW (HP * WP)        // 576
#define DIM 768
#define D4 (DIM / 4)        // 192 float4 per row
#define BATCH 4
#define NBOX 50
#define ROI_L (HP * WP)     // 576

// ---------------------------------------------------------------------------
// Kernel 1: temporal mean  [B, HW*T, D] -> sp [B, HW, D]
// sp[b, hw, d] = mean_t in[b, hw*T + t, d]
// One float4 per thread; output float4 index == global thread index.
// ---------------------------------------------------------------------------
__global__ void __launch_bounds__(256)
temporal_mean_kernel(const float* __restrict__ in, float* __restrict__ sp) {
    int i = blockIdx.x * blockDim.x + threadIdx.x;
    const int total = BATCH * HW * D4;
    if (i >= total) return;
    int d4 = i % D4;
    int rest = i / D4;
    int hw = rest % HW;
    int b = rest / HW;

    const float4* src =
        (const float4*)(in + ((size_t)(b * HW * TF + hw * TF)) * DIM) + d4;
    float4 acc = make_float4(0.f, 0.f, 0.f, 0.f);
#pragma unroll
    for (int t = 0; t < TF; ++t) {
        float4 v = src[(size_t)t * D4];
        acc.x += v.x; acc.y += v.y; acc.z += v.z; acc.w += v.w;
    }
    acc.x /= 9.0f; acc.y /= 9.0f; acc.z /= 9.0f; acc.w /= 9.0f;
    ((float4*)sp)[i] = acc;
}

// ---------------------------------------------------------------------------
// Kernel 2: ROI gather + mask.
// One block (192 threads) per (b, n, chunk-of-4 l values).
// Geometry computed redundantly by all threads (broadcast bbox load).
// ---------------------------------------------------------------------------
__global__ void __launch_bounds__(192)
roi_gather_kernel(const float* __restrict__ sp, const float* __restrict__ bboxes,
                  float* __restrict__ out_feat, float* __restrict__ out_mask) {
    const int LCHUNKS = ROI_L / 4;  // 144
    int bid = blockIdx.x;           // [0, B*N*LCHUNKS)
    int ln = bid % LCHUNKS;
    int rest = bid / LCHUNKS;
    int n = rest % NBOX;
    int b = rest / NBOX;
    int tid = threadIdx.x;          // 0..191

    float4 bb = ((const float4*)bboxes)[b * NBOX + n];
    float cx = bb.x, cy = bb.y, bw = bb.z, bh = bb.w;
    float bwp = bw * 1.2f;
    float bhp = bh * 1.2f;

    // astype(int32) truncates toward zero == C (int) cast
    int col_start = max((int)((cx - bwp * 0.5f) * (float)WP), 0);
    int col_end   = min((int)((cx + bwp * 0.5f) * (float)WP), WP);
    int row_start = max((int)((cy - bhp * 0.5f) * (float)HP), 0);
    int row_end   = min((int)((cy + bhp * 0.5f) * (float)HP), HP);

    // (a+b)/2 then trunc; a,b >= 0 so >>1 is exact
    int col_mid = (col_start + col_end) >> 1;
    int row_mid = (row_start + row_end) >> 1;
    // half_min = MIN_PATCHES/2 = 1
    col_start = min(col_start, max(col_mid - 1, 0));
    col_end   = max(col_end,   min(col_mid + 2, WP));
    row_start = min(row_start, max(row_mid - 1, 0));
    row_end   = max(row_end,   min(row_mid + 2, HP));

    int h = max(row_end - row_start, 0);
    int w = max(col_end - col_start, 0);
    int area = h * w;
    int wsafe = max(w, 1);

    size_t out_base = (size_t)(b * NBOX + n) * ROI_L;  // in rows
    float4* outf4 = (float4*)out_feat;

#pragma unroll
    for (int sub = 0; sub < 4; ++sub) {
        int l = ln * 4 + sub;
        bool valid = l < area;
        float4 v = make_float4(0.f, 0.f, 0.f, 0.f);
        if (valid) {
            int r = row_start + l / wsafe;
            int c = col_start + l % wsafe;
            // when valid, r in [row_start, row_end-1] ⊂ [0,23]; same for c —
            // the reference's clip is a no-op on valid elements.
            const float4* srow =
                (const float4*)sp + (size_t)(b * HW + r * WP + c) * D4;
            v = srow[tid];
        }
        outf4[(out_base + l) * D4 + tid] = v;
        if (tid == 0) {
            out_mask[out_base + l] = valid ? 0.0f : 1.0f;  // True(=1) = padding
        }
    }
}

extern "C" void kernel_launch(void* const* d_in, const int* in_sizes, int n_in,
                              void* d_out, int out_size, void* d_ws, size_t ws_size,
                              hipStream_t stream) {
    const float* spatial = (const float*)d_in[0];   // [B, HW*T, D] fp32
    const float* bboxes  = (const float*)d_in[1];   // [B, N, 4] fp32

    float* sp = (float*)d_ws;                       // [B, HW, D] fp32 (6.9 MB)

    float* out_feat = (float*)d_out;                               // [B,N,L,D]
    float* out_mask = (float*)d_out + (size_t)BATCH * NBOX * ROI_L * DIM;  // [B,N,L]

    {
        int total = BATCH * HW * D4;            // 442368
        int block = 256;
        int grid = (total + block - 1) / block; // 1728
        temporal_mean_kernel<<<grid, block, 0, stream>>>(spatial, sp);
    }
    {
        int grid = BATCH * NBOX * (ROI_L / 4);  // 28800
        roi_gather_kernel<<<grid, 192, 0, stream>>>(sp, bboxes, out_feat, out_mask);
    }
}